// Round 1
// baseline (1355.458 us; speedup 1.0000x reference)
//
#include <hip/hip_runtime.h>

// Chebyshev GCN layer on MI355X.
// out = sum_k S_k @ (X @ W_k) + bias
//   Phase 0: out[n,j] = bias[j]
//   Phase k: Y = X @ W_k  (dense, W_k staged in LDS)
//            for each edge e in support k: out[row_e, :] += val_e * Y[col_e, :]
//            (wave-per-edge, lane-per-feature, f32 atomicAdd)

__global__ __launch_bounds__(256) void init_out_kernel(
    float* __restrict__ out, const float* __restrict__ bias, int total4) {
  __shared__ float4 b4[16];
  if (threadIdx.x < 16)
    b4[threadIdx.x] = reinterpret_cast<const float4*>(bias)[threadIdx.x];
  __syncthreads();
  float4* o4 = reinterpret_cast<float4*>(out);
  for (int i = blockIdx.x * blockDim.x + threadIdx.x; i < total4;
       i += gridDim.x * blockDim.x)
    o4[i] = b4[i & 15];  // 16 float4 per 64-wide row
}

// Y[n, j] = sum_i X[n, i] * Wk[i, j]   (Wk is 64x64 row-major)
__global__ __launch_bounds__(256) void xw64_kernel(
    const float* __restrict__ X, const float* __restrict__ Wk,
    float* __restrict__ Y, int N) {
  __shared__ float Ws[64][64];  // 16 KB; [i][j], lane j consecutive -> conflict-free
  for (int idx = threadIdx.x; idx < 64 * 64; idx += 256)
    Ws[idx >> 6][idx & 63] = Wk[idx];
  __syncthreads();
  const int lane = threadIdx.x & 63;
  const int wid = threadIdx.x >> 6;  // wave id in block, 0..3
  const int stride = gridDim.x * 4;
  for (int n = blockIdx.x * 4 + wid; n < N; n += stride) {
    const float4* xr = reinterpret_cast<const float4*>(X + (size_t)n * 64);
    float acc = 0.f;
#pragma unroll
    for (int i4 = 0; i4 < 16; ++i4) {
      float4 x = xr[i4];  // uniform across wave -> broadcast load
      const int i = i4 * 4;
      acc += x.x * Ws[i][lane] + x.y * Ws[i + 1][lane] +
             x.z * Ws[i + 2][lane] + x.w * Ws[i + 3][lane];
    }
    Y[(size_t)n * 64 + lane] = acc;
  }
}

// One wave per edge; lane f handles feature f. Coalesced 256B gather from Y,
// 64 consecutive f32 atomicAdds into out (fire-and-forget, no waitcnt).
__global__ __launch_bounds__(256) void scatter_kernel(
    const int* __restrict__ rows, const int* __restrict__ cols,
    const float* __restrict__ vals, const float* __restrict__ Y,
    float* __restrict__ out, int E) {
  const int lane = threadIdx.x & 63;
  const int w = (int)((blockIdx.x * blockDim.x + threadIdx.x) >> 6);
  const int nw = (int)((gridDim.x * blockDim.x) >> 6);
  for (int e = w; e < E; e += nw) {
    const int col = cols[e];   // uniform-address broadcast loads
    const int row = rows[e];
    const float v = vals[e];
    const float y = Y[(size_t)col * 64 + lane];
    atomicAdd(out + (size_t)row * 64 + lane, v * y);
  }
}

extern "C" void kernel_launch(void* const* d_in, const int* in_sizes, int n_in,
                              void* d_out, int out_size, void* d_ws, size_t ws_size,
                              hipStream_t stream) {
  const float* X    = (const float*)d_in[0];  // [N, 64]
  const int*   rows = (const int*)d_in[1];    // [3, E]
  const int*   cols = (const int*)d_in[2];    // [3, E]
  const float* vals = (const float*)d_in[3];  // [3, E]
  const float* W    = (const float*)d_in[4];  // [192, 64]
  const float* bias = (const float*)d_in[5];  // [64]
  float* out = (float*)d_out;                 // [N, 64] f32

  const int N = in_sizes[0] / 64;
  const int E = in_sizes[1] / 3;
  float* Y = (float*)d_ws;  // [N, 64] f32 scratch = 25.6 MB

  init_out_kernel<<<1024, 256, 0, stream>>>(out, bias, (N * 64) / 4);
  for (int k = 0; k < 3; ++k) {
    xw64_kernel<<<2048, 256, 0, stream>>>(X, W + (size_t)k * 64 * 64, Y, N);
    scatter_kernel<<<2048, 256, 0, stream>>>(
        rows + (size_t)k * E, cols + (size_t)k * E, vals + (size_t)k * E,
        Y, out, E);
  }
}